// Round 1
// baseline (226.705 us; speedup 1.0000x reference)
//
#include <hip/hip_runtime.h>

// SplatAwareFeedForward on MI355X (gfx950).
// Pipeline: cast/transpose to bf16 -> route tokens by expert -> 4 MFMA GEMM passes.
// Workspace layout (bytes), total ~96.5 MB:
//   xb    @ 0        : 33,554,432  (B*S*D bf16; reused as g-buffer for GEMM4 input)
//   w1t   @ 33554432 :  8,388,608  (E*[H][D] bf16, transposed W1)
//   w2t   @ 41943040 :  8,388,608  (E*[D][H] bf16, transposed W2)
//   wg1t  @ 50331648 :  2,097,152  ([D][D] bf16, transposed Wg1)
//   wg2t  @ 52428800 :  2,097,152  ([D][D] bf16, transposed Wg2)
//   hbuf  @ 54525952 :  8,388,608  (B*S*H bf16, expert-sorted hidden)
//   rout  @ 62914560 : 33,554,432  (B*S*D bf16, routed output, natural order)
//   offs  @ 96468992 : 68          (E+1 ints)
//   order @ 96469248 : 16,384      (S ints, token s-indices sorted by expert)

#define DEV __device__ __forceinline__

typedef float f32x4 __attribute__((ext_vector_type(4)));
typedef short short8 __attribute__((ext_vector_type(8)));

DEV unsigned short f2bf(float f) {
  unsigned u = __float_as_uint(f);
  u += 0x7fffu + ((u >> 16) & 1u);   // round-to-nearest-even
  return (unsigned short)(u >> 16);
}

DEV void gload_lds16(const void* g, void* l) {
  __builtin_amdgcn_global_load_lds(
      (const __attribute__((address_space(1))) unsigned int*)g,
      (__attribute__((address_space(3))) unsigned int*)l, 16, 0, 0);
}

DEV float gelu_exact(float v) {
  return 0.5f * v * (1.0f + erff(v * 0.70710678118654752f));
}

// ---------------- cast fp32 -> bf16 (vectorized) ----------------
__global__ __launch_bounds__(256) void cast_bf16_kernel(
    const float* __restrict__ in, unsigned short* __restrict__ out, long n) {
  long i = ((long)blockIdx.x * 256 + threadIdx.x) * 8;
  if (i >= n) return;
  float4 v0 = *(const float4*)(in + i);
  float4 v1 = *(const float4*)(in + i + 4);
  uint4 o;
  o.x = (unsigned)f2bf(v0.x) | ((unsigned)f2bf(v0.y) << 16);
  o.y = (unsigned)f2bf(v0.z) | ((unsigned)f2bf(v0.w) << 16);
  o.z = (unsigned)f2bf(v1.x) | ((unsigned)f2bf(v1.y) << 16);
  o.w = (unsigned)f2bf(v1.z) | ((unsigned)f2bf(v1.w) << 16);
  *(uint4*)(out + i) = o;
}

// ---------------- transpose-cast: in [R][C] f32 -> out [C][R] bf16, E matrices ----------------
__global__ __launch_bounds__(256) void tcast_kernel(
    const float* __restrict__ in, unsigned short* __restrict__ out,
    int R, int C, long stride) {
  __shared__ float tile[64][65];                   // +1 pad: conflict-free both phases
  const int t = threadIdx.x;
  const long base = (long)blockIdx.z * stride;
  const int r0 = blockIdx.y * 64, c0 = blockIdx.x * 64;
  const int cc = t & 63, rr = t >> 6;
#pragma unroll
  for (int i = 0; i < 16; i++) {
    int r = rr + i * 4;
    tile[r][cc] = in[base + (long)(r0 + r) * C + (c0 + cc)];
  }
  __syncthreads();
#pragma unroll
  for (int i = 0; i < 16; i++) {
    int c = rr + i * 4;
    out[base + (long)(c0 + c) * R + (r0 + cc)] = f2bf(tile[cc][c]);
  }
}

// ---------------- routing: counts -> prefix -> sorted order ----------------
__global__ __launch_bounds__(256) void route_kernel(
    const int* __restrict__ sid, int S, int* __restrict__ offs, int* __restrict__ order) {
  __shared__ int cnt[16], cur[16];
  const int t = threadIdx.x;
  if (t < 16) cnt[t] = 0;
  __syncthreads();
  for (int s = t; s < S; s += 256) atomicAdd(&cnt[sid[s]], 1);
  __syncthreads();
  if (t == 0) {
    int a = 0;
    for (int e = 0; e < 16; e++) { offs[e] = a; cur[e] = a; a += cnt[e]; }
    offs[16] = a;
  }
  __syncthreads();
  for (int s = t; s < S; s += 256) {
    int p = atomicAdd(&cur[sid[s]], 1);
    order[p] = s;
  }
}

// ---------------- 128x128x64 bf16 MFMA GEMM (m97-style 2-barrier loop) ----------------
// A: [rows][K] bf16 (row-major), BT: [N][K] bf16 (i.e. B transposed), C: [rows][N].
// EXPERT: per-blockIdx.z expert, M range from offs[]; GATHER_A: A row via order[];
// SCATTER_C: C row via order[]; GELU: exact-erf GELU epilogue; OUT_F32: fp32 store.
template <bool EXPERT, bool GATHER_A, bool SCATTER_C, bool GELU, bool OUT_F32>
__global__ __launch_bounds__(256) void gemm_mfma(
    const unsigned short* __restrict__ A, const unsigned short* __restrict__ BT,
    const float* __restrict__ bias, void* __restrict__ Cout,
    int M, int N, int K,
    const int* __restrict__ order, const int* __restrict__ offs,
    int S, long btStride, int biasStride) {
  const int t = (int)threadIdx.x;
  const int lane = t & 63;
  const int w = t >> 6;
  const int wm = w >> 1, wn = w & 1;
  const int tileN = (int)blockIdx.x, tileM = (int)blockIdx.y, e = (int)blockIdx.z;

  int rowBase = 0, Me = M;
  const unsigned short* bt = BT;
  const float* bs = bias;
  if (EXPERT) {
    const int o0 = offs[e], o1 = offs[e + 1];
    rowBase = 4 * o0;                 // 4 batch rows per sorted s-position
    Me = 4 * (o1 - o0);
    if (tileM * 128 >= Me) return;    // over-provisioned grid: early exit
    bt += (long)e * btStride;
    bs += (long)e * biasStride;
  }

  __shared__ __align__(16) unsigned short lA[128 * 64];
  __shared__ __align__(16) unsigned short lB[128 * 64];

  // Per-thread staging source pointers (4 issues of global_load_lds x16B each for A and B).
  // LDS dest is linear [row][k]; the XOR swizzle (byte ^= (row&7)<<4) is pre-applied to
  // the GLOBAL source offset so swizzled data lands at linear positions (both-sides rule).
  const unsigned short* aSrc[4];
  const unsigned short* bSrc[4];
  {
    const int q = t & 7;
#pragma unroll
    for (int i = 0; i < 4; i++) {
      const int row = i * 32 + (t >> 3);                       // 0..127
      const int koff = ((q * 16) ^ ((row & 7) << 4)) >> 1;     // element offset in row
      long arow;
      const int lrow = tileM * 128 + row;
      if (EXPERT) {
        const int rr = (lrow < Me) ? lrow : (Me - 1);          // clamp tail rows (discarded)
        const int g = rowBase + rr;
        if (GATHER_A) {
          const int s = order[g >> 2];
          arow = (long)(g & 3) * S + s;                        // x row (b,s)
        } else {
          arow = g;                                            // sorted hidden row
        }
      } else {
        arow = lrow;
      }
      aSrc[i] = A + arow * (long)K + koff;
      const int col = tileN * 128 + row;
      bSrc[i] = bt + (long)col * K + koff;
    }
  }

  f32x4 acc[4][4] = {};

  const int KT = K >> 6;
  for (int kt = 0; kt < KT; kt++) {
    __syncthreads();                       // previous compute done before overwrite
#pragma unroll
    for (int i = 0; i < 4; i++) {
      gload_lds16(aSrc[i] + (kt << 6), (void*)(lA + i * 2048 + w * 512));
      gload_lds16(bSrc[i] + (kt << 6), (void*)(lB + i * 2048 + w * 512));
    }
    __syncthreads();                       // drains vmcnt: tiles ready
#pragma unroll
    for (int kk = 0; kk < 2; kk++) {
      short8 af[4], bfr[4];
      const int kbyte = kk * 64 + (lane >> 4) * 16;
#pragma unroll
      for (int mi = 0; mi < 4; mi++) {
        const int row = wm * 64 + mi * 16 + (lane & 15);
        const int off = row * 128 + (kbyte ^ ((row & 7) << 4));
        af[mi] = *(const short8*)((const char*)lA + off);
      }
#pragma unroll
      for (int ni = 0; ni < 4; ni++) {
        const int row = wn * 64 + ni * 16 + (lane & 15);
        const int off = row * 128 + (kbyte ^ ((row & 7) << 4));
        bfr[ni] = *(const short8*)((const char*)lB + off);
      }
#pragma unroll
      for (int mi = 0; mi < 4; mi++)
#pragma unroll
        for (int ni = 0; ni < 4; ni++)
          acc[mi][ni] = __builtin_amdgcn_mfma_f32_16x16x32_bf16(af[mi], bfr[ni], acc[mi][ni], 0, 0, 0);
    }
  }

  // Epilogue. C/D layout (HW-verified): col = lane&15, row = (lane>>4)*4 + reg.
  float bcol[4];
#pragma unroll
  for (int ni = 0; ni < 4; ni++)
    bcol[ni] = bs[tileN * 128 + wn * 64 + ni * 16 + (lane & 15)];

#pragma unroll
  for (int mi = 0; mi < 4; mi++) {
#pragma unroll
    for (int j = 0; j < 4; j++) {
      const int lrow = tileM * 128 + wm * 64 + mi * 16 + ((lane >> 4) * 4) + j;
      bool valid = true;
      long crow;
      if (EXPERT) {
        valid = (lrow < Me);
        const int g = rowBase + (valid ? lrow : 0);
        if (SCATTER_C) {
          crow = (long)(g & 3) * S + order[g >> 2];            // natural (b,s) row
        } else {
          crow = g;                                            // sorted row
        }
      } else {
        crow = lrow;
      }
      if (!valid) continue;
#pragma unroll
      for (int ni = 0; ni < 4; ni++) {
        float v = acc[mi][ni][j] + bcol[ni];
        if (GELU) v = gelu_exact(v);
        const long cidx = crow * (long)N + tileN * 128 + wn * 64 + ni * 16 + (lane & 15);
        if (OUT_F32) ((float*)Cout)[cidx] = v;
        else ((unsigned short*)Cout)[cidx] = f2bf(v);
      }
    }
  }
}

extern "C" void kernel_launch(void* const* d_in, const int* in_sizes, int n_in,
                              void* d_out, int out_size, void* d_ws, size_t ws_size,
                              hipStream_t stream) {
  const float* x   = (const float*)d_in[0];
  const int*   sid = (const int*)d_in[1];
  const float* W1  = (const float*)d_in[2];
  const float* b1  = (const float*)d_in[3];
  const float* W2  = (const float*)d_in[4];
  const float* b2  = (const float*)d_in[5];
  const float* Wg1 = (const float*)d_in[6];
  const float* bg1 = (const float*)d_in[7];
  const float* Wg2 = (const float*)d_in[8];
  const float* bg2 = (const float*)d_in[9];
  (void)in_sizes; (void)n_in; (void)out_size; (void)ws_size;

  constexpr int E = 16, D = 1024, H = 256, S = 4096, B = 4;
  constexpr long NT = (long)B * S;  // 16384 token rows

  char* ws = (char*)d_ws;
  unsigned short* xb   = (unsigned short*)(ws);
  unsigned short* w1t  = (unsigned short*)(ws + 33554432);
  unsigned short* w2t  = (unsigned short*)(ws + 41943040);
  unsigned short* wg1t = (unsigned short*)(ws + 50331648);
  unsigned short* wg2t = (unsigned short*)(ws + 52428800);
  unsigned short* hbuf = (unsigned short*)(ws + 54525952);
  unsigned short* rout = (unsigned short*)(ws + 62914560);
  int* offs  = (int*)(ws + 96468992);
  int* order = (int*)(ws + 96469248);

  // casts + routing (independent, serialized on stream)
  cast_bf16_kernel<<<dim3((unsigned)(NT * D / 2048)), 256, 0, stream>>>(x, xb, NT * D);
  tcast_kernel<<<dim3(H / 64, D / 64, E), 256, 0, stream>>>(W1, w1t, D, H, (long)D * H);
  tcast_kernel<<<dim3(D / 64, H / 64, E), 256, 0, stream>>>(W2, w2t, H, D, (long)D * H);
  tcast_kernel<<<dim3(D / 64, D / 64, 1), 256, 0, stream>>>(Wg1, wg1t, D, D, (long)D * D);
  tcast_kernel<<<dim3(D / 64, D / 64, 1), 256, 0, stream>>>(Wg2, wg2t, D, D, (long)D * D);
  route_kernel<<<1, 256, 0, stream>>>(sid, S, offs, order);

  // GEMM1: h = gelu(gather(x) @ W1[e] + b1[e])   [sorted rows, bf16]
  gemm_mfma<true, true, false, true, false><<<dim3(H / 128, 128, E), 256, 0, stream>>>(
      xb, w1t, b1, hbuf, (int)NT, H, D, order, offs, S, (long)H * D, H);
  // GEMM2: routed = h @ W2[e] + b2[e]            [scatter to natural rows, bf16]
  gemm_mfma<true, false, true, false, false><<<dim3(D / 128, 128, E), 256, 0, stream>>>(
      hbuf, w2t, b2, rout, (int)NT, D, H, order, offs, S, (long)D * H, D);
  // GEMM3: g = gelu(routed @ Wg1 + bg1)          [bf16, reuses xb buffer]
  gemm_mfma<false, false, false, true, false><<<dim3(D / 128, (unsigned)(NT / 128), 1), 256, 0, stream>>>(
      rout, wg1t, bg1, xb, (int)NT, D, D, nullptr, nullptr, S, 0, 0);
  // GEMM4: out = g @ Wg2 + bg2                   [fp32 to d_out]
  gemm_mfma<false, false, false, false, true><<<dim3(D / 128, (unsigned)(NT / 128), 1), 256, 0, stream>>>(
      xb, wg2t, bg2, d_out, (int)NT, D, D, nullptr, nullptr, S, 0, 0);
}

// Round 2
// 208.295 us; speedup vs baseline: 1.0884x; 1.0884x over previous
//
#include <hip/hip_runtime.h>

// SplatAwareFeedForward on MI355X (gfx950).
// Pipeline: cast/transpose to bf16 -> route tokens by expert -> expert GEMMs (m97-style)
//           -> dense aggregator GEMMs (256x128x64, 3-deep counted-vmcnt pipeline).
// Workspace layout (bytes), total ~96.5 MB:
//   xb    @ 0        : 33,554,432  (B*S*D bf16; reused as g-buffer for GEMM4 input)
//   w1t   @ 33554432 :  8,388,608  (E*[H][D] bf16, transposed W1)
//   w2t   @ 41943040 :  8,388,608  (E*[D][H] bf16, transposed W2)
//   wg1t  @ 50331648 :  2,097,152  ([D][D] bf16, transposed Wg1)
//   wg2t  @ 52428800 :  2,097,152  ([D][D] bf16, transposed Wg2)
//   hbuf  @ 54525952 :  8,388,608  (B*S*H bf16, expert-sorted hidden)
//   rout  @ 62914560 : 33,554,432  (B*S*D bf16, routed output, natural order)
//   offs  @ 96468992 : 68          (E+1 ints)
//   order @ 96469248 : 16,384      (S ints, token s-indices sorted by expert)

#define DEV __device__ __forceinline__

typedef float f32x4 __attribute__((ext_vector_type(4)));
typedef short short8 __attribute__((ext_vector_type(8)));

DEV unsigned short f2bf(float f) {
  unsigned u = __float_as_uint(f);
  u += 0x7fffu + ((u >> 16) & 1u);   // round-to-nearest-even
  return (unsigned short)(u >> 16);
}

DEV void gload_lds16(const void* g, void* l) {
  __builtin_amdgcn_global_load_lds(
      (const __attribute__((address_space(1))) unsigned int*)g,
      (__attribute__((address_space(3))) unsigned int*)l, 16, 0, 0);
}

DEV float gelu_exact(float v) {
  return 0.5f * v * (1.0f + erff(v * 0.70710678118654752f));
}

// ---------------- cast fp32 -> bf16 (vectorized) ----------------
__global__ __launch_bounds__(256) void cast_bf16_kernel(
    const float* __restrict__ in, unsigned short* __restrict__ out, long n) {
  long i = ((long)blockIdx.x * 256 + threadIdx.x) * 8;
  if (i >= n) return;
  float4 v0 = *(const float4*)(in + i);
  float4 v1 = *(const float4*)(in + i + 4);
  uint4 o;
  o.x = (unsigned)f2bf(v0.x) | ((unsigned)f2bf(v0.y) << 16);
  o.y = (unsigned)f2bf(v0.z) | ((unsigned)f2bf(v0.w) << 16);
  o.z = (unsigned)f2bf(v1.x) | ((unsigned)f2bf(v1.y) << 16);
  o.w = (unsigned)f2bf(v1.z) | ((unsigned)f2bf(v1.w) << 16);
  *(uint4*)(out + i) = o;
}

// ---------------- transpose-cast: in [R][C] f32 -> out [C][R] bf16, E matrices ----------------
__global__ __launch_bounds__(256) void tcast_kernel(
    const float* __restrict__ in, unsigned short* __restrict__ out,
    int R, int C, long stride) {
  __shared__ float tile[64][65];
  const int t = threadIdx.x;
  const long base = (long)blockIdx.z * stride;
  const int r0 = blockIdx.y * 64, c0 = blockIdx.x * 64;
  const int cc = t & 63, rr = t >> 6;
#pragma unroll
  for (int i = 0; i < 16; i++) {
    int r = rr + i * 4;
    tile[r][cc] = in[base + (long)(r0 + r) * C + (c0 + cc)];
  }
  __syncthreads();
#pragma unroll
  for (int i = 0; i < 16; i++) {
    int c = rr + i * 4;
    out[base + (long)(c0 + c) * R + (r0 + cc)] = f2bf(tile[cc][c]);
  }
}

// ---------------- routing: counts -> prefix -> sorted order ----------------
__global__ __launch_bounds__(256) void route_kernel(
    const int* __restrict__ sid, int S, int* __restrict__ offs, int* __restrict__ order) {
  __shared__ int cnt[16], cur[16];
  const int t = threadIdx.x;
  if (t < 16) cnt[t] = 0;
  __syncthreads();
  for (int s = t; s < S; s += 256) atomicAdd(&cnt[sid[s]], 1);
  __syncthreads();
  if (t == 0) {
    int a = 0;
    for (int e = 0; e < 16; e++) { offs[e] = a; cur[e] = a; a += cnt[e]; }
    offs[16] = a;
  }
  __syncthreads();
  for (int s = t; s < S; s += 256) {
    int p = atomicAdd(&cur[sid[s]], 1);
    order[p] = s;
  }
}

// ---------------- expert 128x128x64 bf16 MFMA GEMM (m97-style, unchanged) ----------------
template <bool GATHER_A, bool SCATTER_C, bool GELU, bool OUT_F32>
__global__ __launch_bounds__(256) void gemm_mfma(
    const unsigned short* __restrict__ A, const unsigned short* __restrict__ BT,
    const float* __restrict__ bias, void* __restrict__ Cout,
    int M, int N, int K,
    const int* __restrict__ order, const int* __restrict__ offs,
    int S, long btStride, int biasStride) {
  const int t = (int)threadIdx.x;
  const int lane = t & 63;
  const int w = t >> 6;
  const int wm = w >> 1, wn = w & 1;
  const int tileN = (int)blockIdx.x, tileM = (int)blockIdx.y, e = (int)blockIdx.z;

  const int o0 = offs[e], o1 = offs[e + 1];
  const int rowBase = 4 * o0;
  const int Me = 4 * (o1 - o0);
  if (tileM * 128 >= Me) return;
  const unsigned short* bt = BT + (long)e * btStride;
  const float* bs = bias + (long)e * biasStride;

  __shared__ __align__(16) unsigned short lA[128 * 64];
  __shared__ __align__(16) unsigned short lB[128 * 64];

  const unsigned short* aSrc[4];
  const unsigned short* bSrc[4];
  {
    const int q = t & 7;
#pragma unroll
    for (int i = 0; i < 4; i++) {
      const int row = i * 32 + (t >> 3);
      const int koff = ((q * 16) ^ ((row & 7) << 4)) >> 1;
      long arow;
      const int lrow = tileM * 128 + row;
      const int rr = (lrow < Me) ? lrow : (Me - 1);
      const int g = rowBase + rr;
      if (GATHER_A) {
        const int s = order[g >> 2];
        arow = (long)(g & 3) * S + s;
      } else {
        arow = g;
      }
      aSrc[i] = A + arow * (long)K + koff;
      const int col = tileN * 128 + row;
      bSrc[i] = bt + (long)col * K + koff;
    }
  }

  f32x4 acc[4][4] = {};

  const int KT = K >> 6;
  for (int kt = 0; kt < KT; kt++) {
    __syncthreads();
#pragma unroll
    for (int i = 0; i < 4; i++) {
      gload_lds16(aSrc[i] + (kt << 6), (void*)(lA + i * 2048 + w * 512));
      gload_lds16(bSrc[i] + (kt << 6), (void*)(lB + i * 2048 + w * 512));
    }
    __syncthreads();
#pragma unroll
    for (int kk = 0; kk < 2; kk++) {
      short8 af[4], bfr[4];
      const int kbyte = kk * 64 + (lane >> 4) * 16;
#pragma unroll
      for (int mi = 0; mi < 4; mi++) {
        const int row = wm * 64 + mi * 16 + (lane & 15);
        const int off = row * 128 + (kbyte ^ ((row & 7) << 4));
        af[mi] = *(const short8*)((const char*)lA + off);
      }
#pragma unroll
      for (int ni = 0; ni < 4; ni++) {
        const int row = wn * 64 + ni * 16 + (lane & 15);
        const int off = row * 128 + (kbyte ^ ((row & 7) << 4));
        bfr[ni] = *(const short8*)((const char*)lB + off);
      }
#pragma unroll
      for (int mi = 0; mi < 4; mi++)
#pragma unroll
        for (int ni = 0; ni < 4; ni++)
          acc[mi][ni] = __builtin_amdgcn_mfma_f32_16x16x32_bf16(af[mi], bfr[ni], acc[mi][ni], 0, 0, 0);
    }
  }

  float bcol[4];
#pragma unroll
  for (int ni = 0; ni < 4; ni++)
    bcol[ni] = bs[tileN * 128 + wn * 64 + ni * 16 + (lane & 15)];

#pragma unroll
  for (int mi = 0; mi < 4; mi++) {
#pragma unroll
    for (int j = 0; j < 4; j++) {
      const int lrow = tileM * 128 + wm * 64 + mi * 16 + ((lane >> 4) * 4) + j;
      if (lrow >= Me) continue;
      const int g = rowBase + lrow;
      long crow;
      if (SCATTER_C) crow = (long)(g & 3) * S + order[g >> 2];
      else crow = g;
#pragma unroll
      for (int ni = 0; ni < 4; ni++) {
        float v = acc[mi][ni][j] + bcol[ni];
        if (GELU) v = gelu_exact(v);
        const long cidx = crow * (long)N + tileN * 128 + wn * 64 + ni * 16 + (lane & 15);
        if (OUT_F32) ((float*)Cout)[cidx] = v;
        else ((unsigned short*)Cout)[cidx] = f2bf(v);
      }
    }
  }
}

// ---------------- dense 256x128x64 GEMM, 3-deep counted-vmcnt pipeline ----------------
// C[M][N] = A[M][K] @ BT[N][K]^T (+bias, opt GELU). M%256==0, N%128==0, K%64==0.
// 512 threads = 8 waves (4 along M x 2 along N); per-wave 64x64 output.
// LDS: 3 buffers x (A 256x64 + B 128x64) bf16 = 144 KiB. Stage tile t+2 while
// computing tile t; raw s_barrier (no vmcnt drain) + counted s_waitcnt vmcnt(12).
// Grid must be a multiple of 8; XCD-chunked swizzle, ntile-fastest within chunk.
template <bool GELU, bool OUT_F32>
__global__ __launch_bounds__(512, 2) void gemm_dense256(
    const unsigned short* __restrict__ A, const unsigned short* __restrict__ BT,
    const float* __restrict__ bias, void* __restrict__ Cout,
    int N, int K, int ntiles) {
  __shared__ __align__(16) unsigned short lds[3 * (256 * 64 + 128 * 64)];
  unsigned short* ldsA = lds;                 // 3 x 16384 elems
  unsigned short* ldsB = lds + 3 * 16384;     // 3 x 8192 elems

  const int t = (int)threadIdx.x;
  const int lane = t & 63;
  const int w = t >> 6;
  const int wm = w >> 1;          // 0..3 (M)
  const int wn = w & 1;           // 0..1 (N)

  // XCD-chunked bijective swizzle (gridDim.x % 8 == 0), ntile fastest in chunk.
  const int cpx = (int)gridDim.x >> 3;
  const int swz = ((int)blockIdx.x & 7) * cpx + ((int)blockIdx.x >> 3);
  const int mtile = swz / ntiles, ntile = swz % ntiles;

  // Staging source pointers. LDS dest linear; XOR swizzle (byte ^= (row&7)<<4)
  // pre-applied to global source column (both-sides rule).
  const int koff = (((t & 7) * 16) ^ (((t >> 3) & 7) << 4)) >> 1;  // elements
  const unsigned short* aSrc[4];
  const unsigned short* bSrc[2];
#pragma unroll
  for (int i = 0; i < 4; i++)
    aSrc[i] = A + (long)(mtile * 256 + i * 64 + (t >> 3)) * K + koff;
#pragma unroll
  for (int i = 0; i < 2; i++)
    bSrc[i] = BT + (long)(ntile * 128 + i * 64 + (t >> 3)) * K + koff;
  const int dstOff = (t >> 3) * 64 + (t & 7) * 8;  // elements within buffer

  const int KT = K >> 6;

  auto STAGE = [&](int kt, int bi) {
    unsigned short* ba = ldsA + bi * 16384 + dstOff;
    unsigned short* bb = ldsB + bi * 8192 + dstOff;
    const long ko = (long)kt << 6;
#pragma unroll
    for (int i = 0; i < 4; i++) gload_lds16(aSrc[i] + ko, ba + i * 4096);
#pragma unroll
    for (int i = 0; i < 2; i++) gload_lds16(bSrc[i] + ko, bb + i * 4096);
  };

  f32x4 acc[4][4] = {};

  STAGE(0, 0);
  STAGE(1, 1);

  for (int kt = 0; kt < KT; kt++) {
    const int rd = kt % 3;
    if (kt + 2 < KT) {
      STAGE(kt + 2, (kt + 2) % 3);
      asm volatile("s_waitcnt vmcnt(12)" ::: "memory");   // t+1,t+2 stay in flight
    } else if (kt + 1 < KT) {
      asm volatile("s_waitcnt vmcnt(6)" ::: "memory");
    } else {
      asm volatile("s_waitcnt vmcnt(0)" ::: "memory");
    }
    asm volatile("s_barrier" ::: "memory");               // tile kt ready, no drain

    const unsigned short* ba = ldsA + rd * 16384;
    const unsigned short* bb = ldsB + rd * 8192;
#pragma unroll
    for (int kk = 0; kk < 2; kk++) {
      short8 af[4], bfr[4];
      const int kb = kk * 64 + ((lane >> 4) << 4);
      const int sw = (lane & 7) << 4;
#pragma unroll
      for (int mi = 0; mi < 4; mi++) {
        const int row = wm * 64 + mi * 16 + (lane & 15);
        af[mi] = *(const short8*)((const char*)ba + row * 128 + (kb ^ sw));
      }
#pragma unroll
      for (int ni = 0; ni < 4; ni++) {
        const int row = wn * 64 + ni * 16 + (lane & 15);
        bfr[ni] = *(const short8*)((const char*)bb + row * 128 + (kb ^ sw));
      }
      __builtin_amdgcn_s_setprio(1);
#pragma unroll
      for (int mi = 0; mi < 4; mi++)
#pragma unroll
        for (int ni = 0; ni < 4; ni++)
          acc[mi][ni] = __builtin_amdgcn_mfma_f32_16x16x32_bf16(af[mi], bfr[ni], acc[mi][ni], 0, 0, 0);
      __builtin_amdgcn_s_setprio(0);
    }
    asm volatile("s_waitcnt lgkmcnt(0)" ::: "memory");    // my ds_reads done
    asm volatile("s_barrier" ::: "memory");               // safe to overwrite rd next iter
  }

  // Epilogue. C/D layout: col = lane&15, row = (lane>>4)*4 + reg.
  float bcol[4];
#pragma unroll
  for (int ni = 0; ni < 4; ni++)
    bcol[ni] = bias[ntile * 128 + wn * 64 + ni * 16 + (lane & 15)];

#pragma unroll
  for (int mi = 0; mi < 4; mi++) {
#pragma unroll
    for (int j = 0; j < 4; j++) {
      const long crow = mtile * 256 + wm * 64 + mi * 16 + ((lane >> 4) * 4) + j;
#pragma unroll
      for (int ni = 0; ni < 4; ni++) {
        float v = acc[mi][ni][j] + bcol[ni];
        if (GELU) v = gelu_exact(v);
        const long cidx = crow * (long)N + ntile * 128 + wn * 64 + ni * 16 + (lane & 15);
        if (OUT_F32) ((float*)Cout)[cidx] = v;
        else ((unsigned short*)Cout)[cidx] = f2bf(v);
      }
    }
  }
}

extern "C" void kernel_launch(void* const* d_in, const int* in_sizes, int n_in,
                              void* d_out, int out_size, void* d_ws, size_t ws_size,
                              hipStream_t stream) {
  const float* x   = (const float*)d_in[0];
  const int*   sid = (const int*)d_in[1];
  const float* W1  = (const float*)d_in[2];
  const float* b1  = (const float*)d_in[3];
  const float* W2  = (const float*)d_in[4];
  const float* b2  = (const float*)d_in[5];
  const float* Wg1 = (const float*)d_in[6];
  const float* bg1 = (const float*)d_in[7];
  const float* Wg2 = (const float*)d_in[8];
  const float* bg2 = (const float*)d_in[9];
  (void)in_sizes; (void)n_in; (void)out_size; (void)ws_size;

  constexpr int E = 16, D = 1024, H = 256, S = 4096, B = 4;
  constexpr long NT = (long)B * S;  // 16384 token rows

  char* ws = (char*)d_ws;
  unsigned short* xb   = (unsigned short*)(ws);
  unsigned short* w1t  = (unsigned short*)(ws + 33554432);
  unsigned short* w2t  = (unsigned short*)(ws + 41943040);
  unsigned short* wg1t = (unsigned short*)(ws + 50331648);
  unsigned short* wg2t = (unsigned short*)(ws + 52428800);
  unsigned short* hbuf = (unsigned short*)(ws + 54525952);
  unsigned short* rout = (unsigned short*)(ws + 62914560);
  int* offs  = (int*)(ws + 96468992);
  int* order = (int*)(ws + 96469248);

  cast_bf16_kernel<<<dim3((unsigned)(NT * D / 2048)), 256, 0, stream>>>(x, xb, NT * D);
  tcast_kernel<<<dim3(H / 64, D / 64, E), 256, 0, stream>>>(W1, w1t, D, H, (long)D * H);
  tcast_kernel<<<dim3(D / 64, H / 64, E), 256, 0, stream>>>(W2, w2t, H, D, (long)D * H);
  tcast_kernel<<<dim3(D / 64, D / 64, 1), 256, 0, stream>>>(Wg1, wg1t, D, D, (long)D * D);
  tcast_kernel<<<dim3(D / 64, D / 64, 1), 256, 0, stream>>>(Wg2, wg2t, D, D, (long)D * D);
  route_kernel<<<1, 256, 0, stream>>>(sid, S, offs, order);

  // GEMM1: h = gelu(gather(x) @ W1[e] + b1[e])   [sorted rows, bf16]
  gemm_mfma<true, false, true, false><<<dim3(H / 128, 128, E), 256, 0, stream>>>(
      xb, w1t, b1, hbuf, (int)NT, H, D, order, offs, S, (long)H * D, H);
  // GEMM2: routed = h @ W2[e] + b2[e]            [scatter to natural rows, bf16]
  gemm_mfma<false, true, false, false><<<dim3(D / 128, 128, E), 256, 0, stream>>>(
      hbuf, w2t, b2, rout, (int)NT, D, H, order, offs, S, (long)D * H, D);
  // GEMM3: g = gelu(routed @ Wg1 + bg1)          [bf16, reuses xb buffer]
  gemm_dense256<true, false><<<dim3((unsigned)(NT / 256) * (D / 128)), 512, 0, stream>>>(
      rout, wg1t, bg1, xb, D, D, D / 128);
  // GEMM4: out = g @ Wg2 + bg2                   [fp32 to d_out]
  gemm_dense256<false, true><<<dim3((unsigned)(NT / 256) * (D / 128)), 512, 0, stream>>>(
      xb, wg2t, bg2, d_out, D, D, D / 128);
}

// Round 3
// 192.856 us; speedup vs baseline: 1.1755x; 1.0801x over previous
//
#include <hip/hip_runtime.h>

// SplatAwareFeedForward on MI355X (gfx950).
// Pipeline: cast/transpose to bf16 -> route tokens by expert -> expert GEMMs (m97-style)
//           -> dense aggregator GEMMs (256x256x64, m201-style 8-phase counted-vmcnt schedule).
// Workspace layout (bytes), total ~96.5 MB:
//   xb    @ 0        : 33,554,432  (B*S*D bf16; reused as g-buffer for GEMM4 input)
//   w1t   @ 33554432 :  8,388,608  (E*[H][D] bf16, transposed W1)
//   w2t   @ 41943040 :  8,388,608  (E*[D][H] bf16, transposed W2)
//   wg1t  @ 50331648 :  2,097,152  ([D][D] bf16, transposed Wg1)
//   wg2t  @ 52428800 :  2,097,152  ([D][D] bf16, transposed Wg2)
//   hbuf  @ 54525952 :  8,388,608  (B*S*H bf16, expert-sorted hidden)
//   rout  @ 62914560 : 33,554,432  (B*S*D bf16, routed output, natural order)
//   offs  @ 96468992 : 68          (E+1 ints)
//   order @ 96469248 : 16,384      (S ints, token s-indices sorted by expert)

#define DEV __device__ __forceinline__

typedef float f32x4 __attribute__((ext_vector_type(4)));
typedef short short8 __attribute__((ext_vector_type(8)));

DEV unsigned short f2bf(float f) {
  unsigned u = __float_as_uint(f);
  u += 0x7fffu + ((u >> 16) & 1u);   // round-to-nearest-even
  return (unsigned short)(u >> 16);
}

DEV void gload_lds16(const void* g, void* l) {
  __builtin_amdgcn_global_load_lds(
      (const __attribute__((address_space(1))) unsigned int*)g,
      (__attribute__((address_space(3))) unsigned int*)l, 16, 0, 0);
}

DEV float gelu_exact(float v) {
  return 0.5f * v * (1.0f + erff(v * 0.70710678118654752f));
}

#define BARRIER() __builtin_amdgcn_s_barrier()
#define LGKM0()   asm volatile("s_waitcnt lgkmcnt(0)" ::: "memory")
#define VMW(n)    asm volatile("s_waitcnt vmcnt(" #n ")" ::: "memory")
#define SB0()     __builtin_amdgcn_sched_barrier(0)

// ---------------- cast fp32 -> bf16 (vectorized) ----------------
__global__ __launch_bounds__(256) void cast_bf16_kernel(
    const float* __restrict__ in, unsigned short* __restrict__ out, long n) {
  long i = ((long)blockIdx.x * 256 + threadIdx.x) * 8;
  if (i >= n) return;
  float4 v0 = *(const float4*)(in + i);
  float4 v1 = *(const float4*)(in + i + 4);
  uint4 o;
  o.x = (unsigned)f2bf(v0.x) | ((unsigned)f2bf(v0.y) << 16);
  o.y = (unsigned)f2bf(v0.z) | ((unsigned)f2bf(v0.w) << 16);
  o.z = (unsigned)f2bf(v1.x) | ((unsigned)f2bf(v1.y) << 16);
  o.w = (unsigned)f2bf(v1.z) | ((unsigned)f2bf(v1.w) << 16);
  *(uint4*)(out + i) = o;
}

// ---------------- transpose-cast: in [R][C] f32 -> out [C][R] bf16, E matrices ----------------
__global__ __launch_bounds__(256) void tcast_kernel(
    const float* __restrict__ in, unsigned short* __restrict__ out,
    int R, int C, long stride) {
  __shared__ float tile[64][65];
  const int t = threadIdx.x;
  const long base = (long)blockIdx.z * stride;
  const int r0 = blockIdx.y * 64, c0 = blockIdx.x * 64;
  const int cc = t & 63, rr = t >> 6;
#pragma unroll
  for (int i = 0; i < 16; i++) {
    int r = rr + i * 4;
    tile[r][cc] = in[base + (long)(r0 + r) * C + (c0 + cc)];
  }
  __syncthreads();
#pragma unroll
  for (int i = 0; i < 16; i++) {
    int c = rr + i * 4;
    out[base + (long)(c0 + c) * R + (r0 + cc)] = f2bf(tile[cc][c]);
  }
}

// ---------------- routing: counts -> prefix -> sorted order ----------------
__global__ __launch_bounds__(256) void route_kernel(
    const int* __restrict__ sid, int S, int* __restrict__ offs, int* __restrict__ order) {
  __shared__ int cnt[16], cur[16];
  const int t = threadIdx.x;
  if (t < 16) cnt[t] = 0;
  __syncthreads();
  for (int s = t; s < S; s += 256) atomicAdd(&cnt[sid[s]], 1);
  __syncthreads();
  if (t == 0) {
    int a = 0;
    for (int e = 0; e < 16; e++) { offs[e] = a; cur[e] = a; a += cnt[e]; }
    offs[16] = a;
  }
  __syncthreads();
  for (int s = t; s < S; s += 256) {
    int p = atomicAdd(&cur[sid[s]], 1);
    order[p] = s;
  }
}

// ---------------- expert 128x128x64 bf16 MFMA GEMM (m97-style, unchanged) ----------------
template <bool GATHER_A, bool SCATTER_C, bool GELU, bool OUT_F32>
__global__ __launch_bounds__(256) void gemm_mfma(
    const unsigned short* __restrict__ A, const unsigned short* __restrict__ BT,
    const float* __restrict__ bias, void* __restrict__ Cout,
    int M, int N, int K,
    const int* __restrict__ order, const int* __restrict__ offs,
    int S, long btStride, int biasStride) {
  const int t = (int)threadIdx.x;
  const int lane = t & 63;
  const int w = t >> 6;
  const int wm = w >> 1, wn = w & 1;
  const int tileN = (int)blockIdx.x, tileM = (int)blockIdx.y, e = (int)blockIdx.z;

  const int o0 = offs[e], o1 = offs[e + 1];
  const int rowBase = 4 * o0;
  const int Me = 4 * (o1 - o0);
  if (tileM * 128 >= Me) return;
  const unsigned short* bt = BT + (long)e * btStride;
  const float* bs = bias + (long)e * biasStride;

  __shared__ __align__(16) unsigned short lA[128 * 64];
  __shared__ __align__(16) unsigned short lB[128 * 64];

  const unsigned short* aSrc[4];
  const unsigned short* bSrc[4];
  {
    const int q = t & 7;
#pragma unroll
    for (int i = 0; i < 4; i++) {
      const int row = i * 32 + (t >> 3);
      const int koff = ((q * 16) ^ ((row & 7) << 4)) >> 1;
      long arow;
      const int lrow = tileM * 128 + row;
      const int rr = (lrow < Me) ? lrow : (Me - 1);
      const int g = rowBase + rr;
      if (GATHER_A) {
        const int s = order[g >> 2];
        arow = (long)(g & 3) * S + s;
      } else {
        arow = g;
      }
      aSrc[i] = A + arow * (long)K + koff;
      const int col = tileN * 128 + row;
      bSrc[i] = bt + (long)col * K + koff;
    }
  }

  f32x4 acc[4][4] = {};

  const int KT = K >> 6;
  for (int kt = 0; kt < KT; kt++) {
    __syncthreads();
#pragma unroll
    for (int i = 0; i < 4; i++) {
      gload_lds16(aSrc[i] + (kt << 6), (void*)(lA + i * 2048 + w * 512));
      gload_lds16(bSrc[i] + (kt << 6), (void*)(lB + i * 2048 + w * 512));
    }
    __syncthreads();
#pragma unroll
    for (int kk = 0; kk < 2; kk++) {
      short8 af[4], bfr[4];
      const int kbyte = kk * 64 + (lane >> 4) * 16;
#pragma unroll
      for (int mi = 0; mi < 4; mi++) {
        const int row = wm * 64 + mi * 16 + (lane & 15);
        const int off = row * 128 + (kbyte ^ ((row & 7) << 4));
        af[mi] = *(const short8*)((const char*)lA + off);
      }
#pragma unroll
      for (int ni = 0; ni < 4; ni++) {
        const int row = wn * 64 + ni * 16 + (lane & 15);
        const int off = row * 128 + (kbyte ^ ((row & 7) << 4));
        bfr[ni] = *(const short8*)((const char*)lB + off);
      }
#pragma unroll
      for (int mi = 0; mi < 4; mi++)
#pragma unroll
        for (int ni = 0; ni < 4; ni++)
          acc[mi][ni] = __builtin_amdgcn_mfma_f32_16x16x32_bf16(af[mi], bfr[ni], acc[mi][ni], 0, 0, 0);
    }
  }

  float bcol[4];
#pragma unroll
  for (int ni = 0; ni < 4; ni++)
    bcol[ni] = bs[tileN * 128 + wn * 64 + ni * 16 + (lane & 15)];

#pragma unroll
  for (int mi = 0; mi < 4; mi++) {
#pragma unroll
    for (int j = 0; j < 4; j++) {
      const int lrow = tileM * 128 + wm * 64 + mi * 16 + ((lane >> 4) * 4) + j;
      if (lrow >= Me) continue;
      const int g = rowBase + lrow;
      long crow;
      if (SCATTER_C) crow = (long)(g & 3) * S + order[g >> 2];
      else crow = g;
#pragma unroll
      for (int ni = 0; ni < 4; ni++) {
        float v = acc[mi][ni][j] + bcol[ni];
        if (GELU) v = gelu_exact(v);
        const long cidx = crow * (long)N + tileN * 128 + wn * 64 + ni * 16 + (lane & 15);
        if (OUT_F32) ((float*)Cout)[cidx] = v;
        else ((unsigned short*)Cout)[cidx] = f2bf(v);
      }
    }
  }
}

// ---------------- dense 256x256x64 GEMM, m201-style 8-phase schedule ----------------
// C[M][N] = A[M][K] @ BT[N][K]^T (+bias, opt GELU). M%256==0, N%256==0, K%128==0.
// 512 threads = 8 waves (2 along M x 4 along N); per-wave 128x64 output (8x4 frags).
// LDS: 8 half-buffers [d][mat][h] of 128x64 bf16 (16 KiB) = 128 KiB.
//   A-half h holds tile rows r with (r>>6)&1==h (rowInHalf = (r&63)+64*(r>>7)).
//   B-half h holds tile cols c with (c>>5)&1==h (colInHalf = (c&31)+32*... see srcB).
// Per K-tile: 4 quadrant phases (mh,nh) = (0,0),(0,1),(1,0),(1,1); B-frags of both
// halves kept in registers (read once per tile). Each phase stages ONE half-buffer
// (2 x global_load_lds); stage slot is >=1 barrier after that half's last reader.
// vmcnt(4) at END of phases 3 and 7, BEFORE the phase barrier -> after that barrier
// ALL waves' staged halves for the next 4 phases are resident (cross-wave safe).
// Stage schedule (iteration i = tiles 2i/buf0, 2i+1/buf1; nx=2i+2, ny=2i+3 clamped):
//   p0: A1(buf1)<-2i+1   p1: A0(buf0)<-nx   p2: B0(buf0)<-nx   p3: B1(buf0)<-nx
//   p4: A1(buf0)<-nx     p5: A0(buf1)<-ny   p6: B0(buf1)<-ny   p7: B1(buf1)<-ny
template <bool GELU, bool OUT_F32>
__global__ __launch_bounds__(512, 2) void gemm_8phase(
    const unsigned short* __restrict__ A, const unsigned short* __restrict__ BT,
    const float* __restrict__ bias, void* __restrict__ Cout,
    int N, int K, int ntiles) {
  __shared__ __align__(16) unsigned short lds[8 * 8192];  // [d][mat][h][128*64]

  const int t = (int)threadIdx.x;
  const int lane = t & 63;
  const int w = t >> 6;
  const int wm = w >> 2;   // 0..1 (M half of tile)
  const int wn = w & 3;    // 0..3 (N quarter of tile)

  // XCD-chunked bijective swizzle (gridDim.x % 8 == 0), ntile fastest in chunk.
  const int cpx = (int)gridDim.x >> 3;
  const int swz = ((int)blockIdx.x & 7) * cpx + ((int)blockIdx.x >> 3);
  const int mtile = swz / ntiles, ntile = swz % ntiles;

  // Staging source pointers [i][h]; XOR swizzle (byte ^= (rowInHalf&7)<<4)
  // pre-applied to the global source column (both-sides rule).
  const int tq = t & 7;
  const unsigned short* srcA[2][2];
  const unsigned short* srcB[2][2];
#pragma unroll
  for (int i = 0; i < 2; i++) {
    const int ir = i * 64 + (t >> 3);                       // rowInHalf
    const int koffE = ((tq * 16) ^ ((ir & 7) << 4)) >> 1;   // element offset
#pragma unroll
    for (int h = 0; h < 2; h++) {
      const int ra = (ir & 63) + (h << 6) + ((ir >> 6) << 7);   // tile row
      srcA[i][h] = A + (long)(mtile * 256 + ra) * K + koffE;
      const int cb = (ir & 31) + (h << 5) + ((ir >> 5) << 6);   // tile col
      srcB[i][h] = BT + (long)(ntile * 256 + cb) * K + koffE;
    }
  }
  const int dstE = (t >> 3) * 64 + tq * 8;  // linear LDS dest (== base + lane*16B)

  auto STAGE = [&](int d, int mat, int h, int kt) {
    unsigned short* dst = lds + ((d * 4 + mat * 2 + h) << 13) + dstE;
    const unsigned short* s0 = (mat == 0 ? srcA[0][h] : srcB[0][h]) + (kt << 6);
    const unsigned short* s1 = (mat == 0 ? srcA[1][h] : srcB[1][h]) + (kt << 6);
    gload_lds16(s0, dst);
    gload_lds16(s1, dst + 4096);
  };

  short8 aReg[8], bReg[8];
  const int klane = (lane >> 4) << 4;
  const int rsw = (lane & 7) << 4;   // rowInHalf&7 == lane&7 for all frag reads

  auto LDA = [&](int d, int mh) {
    const char* base = (const char*)(lds + ((d * 4 + mh) << 13));
    const int r0 = wm * 64 + (lane & 15);
#pragma unroll
    for (int m = 0; m < 4; m++) {
      const int row = r0 + m * 16;
#pragma unroll
      for (int kk = 0; kk < 2; kk++)
        aReg[m * 2 + kk] = *(const short8*)(base + row * 128 + ((kk * 64 + klane) ^ rsw));
    }
  };
  auto LDB = [&](int d, int nh) {
    const char* base = (const char*)(lds + ((d * 4 + 2 + nh) << 13));
    const int r0 = wn * 32 + (lane & 15);
#pragma unroll
    for (int n = 0; n < 2; n++) {
      const int row = r0 + n * 16;
#pragma unroll
      for (int kk = 0; kk < 2; kk++)
        bReg[(nh * 2 + n) * 2 + kk] = *(const short8*)(base + row * 128 + ((kk * 64 + klane) ^ rsw));
    }
  };

  f32x4 acc[8][4] = {};
  auto MMA = [&](int mb, int nb) {   // 4 mi x 2 ni x 2 kk = 16 MFMA
    __builtin_amdgcn_s_setprio(1);
#pragma unroll
    for (int kk = 0; kk < 2; kk++)
#pragma unroll
      for (int m = 0; m < 4; m++)
#pragma unroll
        for (int n = 0; n < 2; n++)
          acc[mb + m][nb + n] = __builtin_amdgcn_mfma_f32_16x16x32_bf16(
              aReg[m * 2 + kk], bReg[(nb + n) * 2 + kk], acc[mb + m][nb + n], 0, 0, 0);
    __builtin_amdgcn_s_setprio(0);
  };

  const int KT = K >> 6;

  // Prologue: buf0 <- tile0 (all 4 halves); buf1 <- tile1 (A0,B0,B1; A1 comes at p0).
  {
    const int t1 = (KT > 1) ? 1 : 0;
    STAGE(0, 0, 0, 0); STAGE(0, 1, 0, 0); STAGE(0, 1, 1, 0); STAGE(0, 0, 1, 0);
    STAGE(1, 0, 0, t1); STAGE(1, 1, 0, t1); STAGE(1, 1, 1, t1);
    VMW(6);            // 14 outstanding -> oldest 8 (all of tile0) done
    BARRIER(); SB0();
  }

  for (int it = 0; it < (KT >> 1); ++it) {
    const int tb = (2 * it + 1 < KT) ? 2 * it + 1 : KT - 1;
    int nx = 2 * it + 2; if (nx >= KT) nx = KT - 1;
    int ny = 2 * it + 3; if (ny >= KT) ny = KT - 1;
    // ---- p0: quadrant (0,0) of buf0 ----
    LDA(0, 0); LDB(0, 0); STAGE(1, 0, 1, tb);
    BARRIER(); LGKM0(); SB0();
    MMA(0, 0);
    BARRIER(); SB0();
    // ---- p1: (0,1) ----
    LDB(0, 1); STAGE(0, 0, 0, nx);
    BARRIER(); LGKM0(); SB0();
    MMA(0, 2);
    BARRIER(); SB0();
    // ---- p2: (1,0) ----
    LDA(0, 1); STAGE(0, 1, 0, nx);
    BARRIER(); LGKM0(); SB0();
    MMA(4, 0);
    BARRIER(); SB0();
    // ---- p3: (1,1) ----
    STAGE(0, 1, 1, nx);
    BARRIER(); LGKM0(); SB0();
    MMA(4, 2);
    VMW(4);            // certifies all halves needed by p4-p7 (incl. other waves after barrier)
    BARRIER(); SB0();
    // ---- p4: quadrant (0,0) of buf1 ----
    LDA(1, 0); LDB(1, 0); STAGE(0, 0, 1, nx);
    BARRIER(); LGKM0(); SB0();
    MMA(0, 0);
    BARRIER(); SB0();
    // ---- p5: (0,1) ----
    LDB(1, 1); STAGE(1, 0, 0, ny);
    BARRIER(); LGKM0(); SB0();
    MMA(0, 2);
    BARRIER(); SB0();
    // ---- p6: (1,0) ----
    LDA(1, 1); STAGE(1, 1, 0, ny);
    BARRIER(); LGKM0(); SB0();
    MMA(4, 0);
    BARRIER(); SB0();
    // ---- p7: (1,1) ----
    STAGE(1, 1, 1, ny);
    BARRIER(); LGKM0(); SB0();
    MMA(4, 2);
    VMW(4);            // certifies all halves needed by next iteration's p0-p3
    BARRIER(); SB0();
  }
  VMW(0);              // drain trailing prefetches before kernel end

  // Epilogue. C/D layout: col = lane&15, row = (lane>>4)*4 + reg.
  float bcol[4];
#pragma unroll
  for (int n = 0; n < 4; n++)
    bcol[n] = bias[ntile * 256 + wn * 64 + n * 16 + (lane & 15)];
  const int cbase = ntile * 256 + wn * 64 + (lane & 15);
#pragma unroll
  for (int m = 0; m < 8; m++) {
#pragma unroll
    for (int j = 0; j < 4; j++) {
      const long crow = mtile * 256 + wm * 128 + m * 16 + ((lane >> 4) << 2) + j;
#pragma unroll
      for (int n = 0; n < 4; n++) {
        float v = acc[m][n][j] + bcol[n];
        if (GELU) v = gelu_exact(v);
        const long cidx = crow * (long)N + cbase + n * 16;
        if (OUT_F32) ((float*)Cout)[cidx] = v;
        else ((unsigned short*)Cout)[cidx] = f2bf(v);
      }
    }
  }
}

extern "C" void kernel_launch(void* const* d_in, const int* in_sizes, int n_in,
                              void* d_out, int out_size, void* d_ws, size_t ws_size,
                              hipStream_t stream) {
  const float* x   = (const float*)d_in[0];
  const int*   sid = (const int*)d_in[1];
  const float* W1  = (const float*)d_in[2];
  const float* b1  = (const float*)d_in[3];
  const float* W2  = (const float*)d_in[4];
  const float* b2  = (const float*)d_in[5];
  const float* Wg1 = (const float*)d_in[6];
  const float* bg1 = (const float*)d_in[7];
  const float* Wg2 = (const float*)d_in[8];
  const float* bg2 = (const float*)d_in[9];
  (void)in_sizes; (void)n_in; (void)out_size; (void)ws_size;

  constexpr int E = 16, D = 1024, H = 256, S = 4096, B = 4;
  constexpr long NT = (long)B * S;  // 16384 token rows

  char* ws = (char*)d_ws;
  unsigned short* xb   = (unsigned short*)(ws);
  unsigned short* w1t  = (unsigned short*)(ws + 33554432);
  unsigned short* w2t  = (unsigned short*)(ws + 41943040);
  unsigned short* wg1t = (unsigned short*)(ws + 50331648);
  unsigned short* wg2t = (unsigned short*)(ws + 52428800);
  unsigned short* hbuf = (unsigned short*)(ws + 54525952);
  unsigned short* rout = (unsigned short*)(ws + 62914560);
  int* offs  = (int*)(ws + 96468992);
  int* order = (int*)(ws + 96469248);

  cast_bf16_kernel<<<dim3((unsigned)(NT * D / 2048)), 256, 0, stream>>>(x, xb, NT * D);
  tcast_kernel<<<dim3(H / 64, D / 64, E), 256, 0, stream>>>(W1, w1t, D, H, (long)D * H);
  tcast_kernel<<<dim3(D / 64, H / 64, E), 256, 0, stream>>>(W2, w2t, H, D, (long)D * H);
  tcast_kernel<<<dim3(D / 64, D / 64, 1), 256, 0, stream>>>(Wg1, wg1t, D, D, (long)D * D);
  tcast_kernel<<<dim3(D / 64, D / 64, 1), 256, 0, stream>>>(Wg2, wg2t, D, D, (long)D * D);
  route_kernel<<<1, 256, 0, stream>>>(sid, S, offs, order);

  // GEMM1: h = gelu(gather(x) @ W1[e] + b1[e])   [sorted rows, bf16]
  gemm_mfma<true, false, true, false><<<dim3(H / 128, 128, E), 256, 0, stream>>>(
      xb, w1t, b1, hbuf, (int)NT, H, D, order, offs, S, (long)H * D, H);
  // GEMM2: routed = h @ W2[e] + b2[e]            [scatter to natural rows, bf16]
  gemm_mfma<false, true, false, false><<<dim3(D / 128, 128, E), 256, 0, stream>>>(
      hbuf, w2t, b2, rout, (int)NT, D, H, order, offs, S, (long)D * H, D);
  // GEMM3: g = gelu(routed @ Wg1 + bg1)          [bf16, reuses xb buffer]
  gemm_8phase<true, false><<<dim3((unsigned)(NT / 256) * (D / 256)), 512, 0, stream>>>(
      rout, wg1t, bg1, xb, D, D, D / 256);
  // GEMM4: out = g @ Wg2 + bg2                   [fp32 to d_out]
  gemm_8phase<false, true><<<dim3((unsigned)(NT / 256) * (D / 256)), 512, 0, stream>>>(
      xb, wg2t, bg2, d_out, D, D, D / 256);
}